// Round 18
// baseline (116.233 us; speedup 1.0000x reference)
//
#include <hip/hip_runtime.h>
#include <math.h>

// R16: fdot2 (3 VALU/pair, validated in R15: absmax 0.03125 passes) restored
// onto the R5 geometry (416 blocks, 8 a-pts/thread). R15's regression was the
// LDS-read:VALU ratio: at 2 pts/thread the wave issued 1 broadcast
// ds_read_b128 per 12 SIMD-cyc of VALU, over the ~8cyc/read LDS pipe ->
// LDS-bound ~23us. At 8 pts/thread: 1 read per 48 cyc -> VALU-bound.
//  * nn: per j: t=fmaf(az,bz,nb2); u=fdot2(axy,bxy,t); fmax  (24 VALU + 1 read)
//  * reduce: R5/R8 verified version (416x2048 partial layout), unchanged.
//  * out: unchanged (measured ~10us, at write-BW floor).
// Known budget: T_fixed=71.7us, out~10, red~2.5, gaps~5.
// Predict nn 22.4 -> ~17.7us; dur 112.2 -> ~105-109; absmax 0.03125.
//
// nn job table (416 blocks; a_tile = 2048 pts, b_tile = 256 pts):
//   [0,128)    cd1:  A=pc1_0(8192) vs B=pc2    4 at x 32 bt
//   [128,256)  cd2:  A=pc2(8192)   vs B=pc1_0  4 at x 32 bt
//   [256,320)  sd1:  A=pc1_1(4096) vs B=pc2    2 at x 32 bt
//   [320,384)  sd2:  A=pc2(8192)   vs B=pc1_1  4 at x 16 bt
//   [384,416)  conf: A=pc3[b] vs B=pc2[b] per batch: 1 at x 8 bt
// Block bid writes 2048 partial clamped-d2 to part[bid*2048 ..).

constexpr int OUT_TOTAL  = 4 * 2048 * 2048;
constexpr int PART_TOTAL = 416 * 2048;              // 851968 floats, 3.4 MB
constexpr int PART_OFS   = OUT_TOTAL - PART_TOTAL;

typedef float nfloat4 __attribute__((ext_vector_type(4)));
typedef _Float16 h2 __attribute__((ext_vector_type(2)));

static __device__ __forceinline__ float pack2h(float x, float y) {
    h2 v; v[0] = (_Float16)x; v[1] = (_Float16)y;
    return __builtin_bit_cast(float, v);
}

__global__ __launch_bounds__(256) void nn_kernel(
    const float* __restrict__ A0,   // pc1_0 flat (8192 pts)
    const float* __restrict__ A1,   // pc1_1 flat (4096 pts)
    const float* __restrict__ P2,   // pc2   flat (8192 pts)
    const float* __restrict__ P3,   // pc3   (4 x 2048 pts)
    float* __restrict__ part)
{
    __shared__ float4 lds[256];     // (bitcast h2(bx,by), bz, -0.5*|b|^2, 0)
    int bid = blockIdx.x;
    const float* A; const float* Bp; int at; int btile;
    if (bid < 128)      { int l = bid;       A = A0; Bp = P2; at = l >> 5; btile = l & 31; }
    else if (bid < 256) { int l = bid - 128; A = P2; Bp = A0; at = l >> 5; btile = l & 31; }
    else if (bid < 320) { int l = bid - 256; A = A1; Bp = P2; at = l >> 5; btile = l & 31; }
    else if (bid < 384) { int l = bid - 320; A = P2; Bp = A1; at = l >> 4; btile = l & 15; }
    else { int l = bid - 384; int b = l >> 3; btile = l & 7; at = 0;
           A = P3 + b * 6144; Bp = P2 + b * 6144; }

    {
        const float* s = Bp + (btile * 256 + threadIdx.x) * 3;
        float bx = s[0], by = s[1], bz = s[2];
        float nb2 = -0.5f * fmaf(bx, bx, fmaf(by, by, bz * bz));
        lds[threadIdx.x] = make_float4(pack2h(bx, by), bz, nb2, 0.f);
    }

    // 8 a-points per thread (24 consecutive floats, 16B-aligned -> 6x float4)
    int a_base = at * 2048 + threadIdx.x * 8;
    const float4* av = (const float4*)(A + a_base * 3);
    float4 v0 = av[0], v1 = av[1], v2 = av[2], v3 = av[3], v4 = av[4], v5 = av[5];
    float ax[8], ay[8], az[8], a2[8], mx[8];
    ax[0]=v0.x; ay[0]=v0.y; az[0]=v0.z;
    ax[1]=v0.w; ay[1]=v1.x; az[1]=v1.y;
    ax[2]=v1.z; ay[2]=v1.w; az[2]=v2.x;
    ax[3]=v2.y; ay[3]=v2.z; az[3]=v2.w;
    ax[4]=v3.x; ay[4]=v3.y; az[4]=v3.z;
    ax[5]=v3.w; ay[5]=v4.x; az[5]=v4.y;
    ax[6]=v4.z; ay[6]=v4.w; az[6]=v5.x;
    ax[7]=v5.y; ay[7]=v5.z; az[7]=v5.w;
    h2 axy[8];
    #pragma unroll
    for (int k = 0; k < 8; k++) {
        a2[k] = fmaf(ax[k], ax[k], fmaf(ay[k], ay[k], az[k]*az[k]));
        axy[k] = __builtin_bit_cast(h2, pack2h(ax[k], ay[k]));
        mx[k] = -3.4e38f;
    }
    __syncthreads();

    // maximize (a.b - 0.5|b|^2); 3 VALU/pair, 24 VALU per broadcast ds_read.
    #pragma unroll 4
    for (int j = 0; j < 256; j++) {
        float4 b = lds[j];
        h2 bxy = __builtin_bit_cast(h2, b.x);
        #pragma unroll
        for (int k = 0; k < 8; k++) {
            float t = fmaf(az[k], b.y, b.z);
            float u = __builtin_amdgcn_fdot2(axy[k], bxy, t, false);
            mx[k] = fmaxf(mx[k], u);
        }
    }
    float4 o0, o1;
    o0.x = fmaxf(fmaf(-2.f, mx[0], a2[0]), 0.f);
    o0.y = fmaxf(fmaf(-2.f, mx[1], a2[1]), 0.f);
    o0.z = fmaxf(fmaf(-2.f, mx[2], a2[2]), 0.f);
    o0.w = fmaxf(fmaf(-2.f, mx[3], a2[3]), 0.f);
    o1.x = fmaxf(fmaf(-2.f, mx[4], a2[4]), 0.f);
    o1.y = fmaxf(fmaf(-2.f, mx[5], a2[5]), 0.f);
    o1.z = fmaxf(fmaf(-2.f, mx[6], a2[6]), 0.f);
    o1.w = fmaxf(fmaf(-2.f, mx[7], a2[7]), 0.f);
    float4* op = (float4*)(part + bid * 2048 + threadIdx.x * 8);
    op[0] = o0;
    op[1] = o1;
}

// 36 blocks x 1024 threads; 1 point per thread. R5/R8 verified version.
__global__ __launch_bounds__(1024) void reduce_kernel(
    const float* __restrict__ part,
    const float* __restrict__ conf_in,   // pc1_3, 8192 values
    float* __restrict__ ws)
{
    int g = blockIdx.x;
    int tid = threadIdx.x;
    int base, bt; float scale; bool isconf = false;
    if (g < 8)       { int at = g >> 1;            base = (at * 32) * 2048       + (g & 1) * 1024; bt = 32; scale = 0.5f / 8192.f; }
    else if (g < 16) { int l = g - 8;  int at = l >> 1; base = (128 + at * 32) * 2048 + (l & 1) * 1024; bt = 32; scale = 0.5f / 8192.f; }
    else if (g < 20) { int l = g - 16; int at = l >> 1; base = (256 + at * 32) * 2048 + (l & 1) * 1024; bt = 32; scale = 1.f / 4096.f; }
    else if (g < 28) { int l = g - 20; int at = l >> 1; base = (320 + at * 16) * 2048 + (l & 1) * 1024; bt = 16; scale = 1.f / 8192.f; }
    else             { int l = g - 28; int b = l >> 1;  base = (384 + b * 8) * 2048   + (l & 1) * 1024; bt = 8;  scale = 1.f / 8192.f; isconf = true; }

    float m = 3.4e38f;
    const float* p = part + base + tid;
    #pragma unroll 4
    for (int t = 0; t < bt; t++, p += 2048) m = fminf(m, p[0]);
    float d = sqrtf(m);
    float sum;
    if (!isconf) {
        sum = d;
    } else {
        float e = conf_in[(g - 28) * 1024 + tid] - __expf(-d);
        sum = e * e;
    }
    #pragma unroll
    for (int ofs = 32; ofs > 0; ofs >>= 1) sum += __shfl_down(sum, ofs);
    __shared__ float red[16];
    if ((tid & 63) == 0) red[tid >> 6] = sum;
    __syncthreads();
    if (tid == 0) {
        float tot = 0.f;
        #pragma unroll
        for (int i = 0; i < 16; i++) tot += red[i];
        ws[g] = tot * scale;
    }
}

// out[b,n,m] = S + 0.5 * dist(pc1_0[b,n], pc2[b,m]).  UNCHANGED (BW floor).
__global__ __launch_bounds__(256) void out_kernel(
    const float* __restrict__ pc1_0,
    const float* __restrict__ pc2,
    const float* __restrict__ wsp,
    float* __restrict__ out)
{
    int blk = blockIdx.x;            // 1024 blocks
    int batch = blk >> 8;
    int n8 = blk & 255;
    int tid = threadIdx.x;
    float S = 0.f;
    #pragma unroll
    for (int t = 0; t < 36; t++) S += wsp[t];   // uniform -> s_loads
    const float* bb = pc2 + batch * 6144;
    float bx[8], by[8], bz[8];
    {
        const float4* p = (const float4*)(bb + tid * 12);
        float4 u0 = p[0], u1 = p[1], u2 = p[2];
        bx[0]=u0.x; by[0]=u0.y; bz[0]=u0.z;
        bx[1]=u0.w; by[1]=u1.x; bz[1]=u1.y;
        bx[2]=u1.z; by[2]=u1.w; bz[2]=u2.x;
        bx[3]=u2.y; by[3]=u2.z; bz[3]=u2.w;
    }
    {
        const float4* p = (const float4*)(bb + 3072 + tid * 12);
        float4 u0 = p[0], u1 = p[1], u2 = p[2];
        bx[4]=u0.x; by[4]=u0.y; bz[4]=u0.z;
        bx[5]=u0.w; by[5]=u1.x; bz[5]=u1.y;
        bx[6]=u1.z; by[6]=u1.w; bz[6]=u2.x;
        bx[7]=u2.y; by[7]=u2.z; bz[7]=u2.w;
    }
    const float* arow = pc1_0 + batch * 6144 + n8 * 24;  // 8 rows x 3 (uniform)
    float* ob = out + (long)((batch << 11) + (n8 << 3)) * 2048 + tid * 4;
    #pragma unroll
    for (int r = 0; r < 8; r++) {
        float axx = arow[r*3], ayy = arow[r*3+1], azz = arow[r*3+2];
        float o[8];
        #pragma unroll
        for (int k = 0; k < 8; k++) {
            float dx = axx - bx[k], dy = ayy - by[k], dz = azz - bz[k];
            float d2 = fmaf(dx, dx, fmaf(dy, dy, dz*dz));
            o[k] = fmaf(0.5f, sqrtf(d2), S);
        }
        nfloat4 lo = { o[0], o[1], o[2], o[3] };
        nfloat4 hi = { o[4], o[5], o[6], o[7] };
        __builtin_nontemporal_store(lo, (nfloat4*)(ob + r * 2048));
        __builtin_nontemporal_store(hi, (nfloat4*)(ob + r * 2048 + 1024));
    }
}

extern "C" void kernel_launch(void* const* d_in, const int* in_sizes, int n_in,
                              void* d_out, int out_size, void* d_ws, size_t ws_size,
                              hipStream_t stream) {
    const float* pc1_0 = (const float*)d_in[0];  // [4,2048,3]
    const float* pc1_1 = (const float*)d_in[1];  // [4,1024,3]
    const float* pc1_3 = (const float*)d_in[2];  // [4,2048,1]
    const float* pc2   = (const float*)d_in[3];  // [4,2048,3]
    const float* pc3   = (const float*)d_in[4];  // [4,2048,3]
    float* out = (float*)d_out;
    float* ws  = (float*)d_ws;                   // ws[0..35]: scaled partial sums
    float* part = out + PART_OFS;                // partial-min scratch in d_out tail

    nn_kernel<<<416, 256, 0, stream>>>(pc1_0, pc1_1, pc2, pc3, part);
    reduce_kernel<<<36, 1024, 0, stream>>>(part, pc1_3, ws);
    out_kernel<<<1024, 256, 0, stream>>>(pc1_0, pc2, ws, out);
}

// Round 19
// 112.267 us; speedup vs baseline: 1.0353x; 1.0353x over previous
//
#include <hip/hip_runtime.h>
#include <math.h>

// R18: nn grid-tail rebalance. fdot2 is DEAD (R16: +4us at same geometry ->
// v_dot2_f32_f16 issues at <=1/2 fma rate). Back to pure-f32 fmaf 4 ops/pair
// (absmax 0.015625). Single change vs R8-best: nn = 1664 blocks x 128 thr x
// 4 pts/thread (512-pt a-tiles). 416 blocks was 1.625 blocks/CU -> 2 rounds,
// ~19% idle tail; 1664 -> 6.5 rounds, ~7.7% tail. Keeps 16 VALU per
// broadcast ds_read_b128 (proven VALU-bound ratio; R15's regression was the
// 4-VALU/read ratio at 2pt/256thr, not the 512-pt tiling).
// reduce = R15/R16 harness-verified version (1664x512 part layout), byte-same.
// out unchanged (at write-BW floor ~10.5us).
// Budget: T_fixed 71.7 | nn 22.4->pred ~19.5 | out 10.5 | red 2.5 | gaps ~5.
// Predict dur 112.2 -> ~109-110; absmax 0.015625.
//
// nn job table (1664 blocks; a_tile = 512 pts, b_tile = 256 pts):
//   [0,512)     cd1:  A=pc1_0(8192) vs B=pc2    16 at x 32 bt
//   [512,1024)  cd2:  A=pc2(8192)   vs B=pc1_0  16 at x 32 bt
//   [1024,1280) sd1:  A=pc1_1(4096) vs B=pc2     8 at x 32 bt
//   [1280,1536) sd2:  A=pc2(8192)   vs B=pc1_1  16 at x 16 bt
//   [1536,1664) conf: per batch b: A=pc3[b] vs B=pc2[b], 4 at x 8 bt
// Block bid writes 512 partial clamped-d2 to part[bid*512 ..).

constexpr int OUT_TOTAL  = 4 * 2048 * 2048;
constexpr int PART_TOTAL = 1664 * 512;              // 851968 floats, 3.4 MB
constexpr int PART_OFS   = OUT_TOTAL - PART_TOTAL;

typedef float nfloat4 __attribute__((ext_vector_type(4)));

__global__ __launch_bounds__(128) void nn_kernel(
    const float* __restrict__ A0,   // pc1_0 flat (8192 pts)
    const float* __restrict__ A1,   // pc1_1 flat (4096 pts)
    const float* __restrict__ P2,   // pc2   flat (8192 pts)
    const float* __restrict__ P3,   // pc3   (4 x 2048 pts)
    float* __restrict__ part)
{
    __shared__ float4 lds[256];     // (bx, by, bz, -0.5*|b|^2)
    int bid = blockIdx.x;
    const float* A; const float* Bp; int at; int btile;
    if (bid < 512)       { int l = bid;        A = A0; Bp = P2; at = l >> 5; btile = l & 31; }
    else if (bid < 1024) { int l = bid - 512;  A = P2; Bp = A0; at = l >> 5; btile = l & 31; }
    else if (bid < 1280) { int l = bid - 1024; A = A1; Bp = P2; at = l >> 5; btile = l & 31; }
    else if (bid < 1536) { int l = bid - 1280; A = P2; Bp = A1; at = l >> 4; btile = l & 15; }
    else { int l = bid - 1536; int b = l >> 5; int l2 = l & 31; at = l2 >> 3; btile = l2 & 7;
           A = P3 + b * 6144; Bp = P2 + b * 6144; }

    // Stage 256 b-points with 128 threads: 2 points each.
    {
        const float* s = Bp + (btile * 256 + threadIdx.x) * 3;
        float bx = s[0], by = s[1], bz = s[2];
        float nb2 = -0.5f * fmaf(bx, bx, fmaf(by, by, bz * bz));
        lds[threadIdx.x] = make_float4(bx, by, bz, nb2);
        const float* s2 = Bp + (btile * 256 + 128 + threadIdx.x) * 3;
        float cx = s2[0], cy = s2[1], cz = s2[2];
        float nc2 = -0.5f * fmaf(cx, cx, fmaf(cy, cy, cz * cz));
        lds[128 + threadIdx.x] = make_float4(cx, cy, cz, nc2);
    }

    // 4 a-points per thread (12 consecutive floats, 48B offset -> 3x float4)
    int a_base = at * 512 + threadIdx.x * 4;
    const float4* av = (const float4*)(A + a_base * 3);
    float4 v0 = av[0], v1 = av[1], v2 = av[2];
    float ax[4], ay[4], az[4], a2[4], mx[4];
    ax[0]=v0.x; ay[0]=v0.y; az[0]=v0.z;
    ax[1]=v0.w; ay[1]=v1.x; az[1]=v1.y;
    ax[2]=v1.z; ay[2]=v1.w; az[2]=v2.x;
    ax[3]=v2.y; ay[3]=v2.z; az[3]=v2.w;
    #pragma unroll
    for (int k = 0; k < 4; k++) {
        a2[k] = fmaf(ax[k], ax[k], fmaf(ay[k], ay[k], az[k]*az[k]));
        mx[k] = -3.4e38f;
    }
    __syncthreads();

    // maximize (a.b - 0.5|b|^2); 4 VALU/pair, 16 VALU per broadcast ds_read.
    #pragma unroll 4
    for (int j = 0; j < 256; j++) {
        float4 b = lds[j];
        #pragma unroll
        for (int k = 0; k < 4; k++) {
            float u = fmaf(az[k], b.z, b.w);
            u = fmaf(ay[k], b.y, u);
            u = fmaf(ax[k], b.x, u);
            mx[k] = fmaxf(mx[k], u);
        }
    }
    float4 o;
    o.x = fmaxf(fmaf(-2.f, mx[0], a2[0]), 0.f);
    o.y = fmaxf(fmaf(-2.f, mx[1], a2[1]), 0.f);
    o.z = fmaxf(fmaf(-2.f, mx[2], a2[2]), 0.f);
    o.w = fmaxf(fmaf(-2.f, mx[3], a2[3]), 0.f);
    *(float4*)(part + bid * 512 + threadIdx.x * 4) = o;
}

// 36 blocks x 1024 threads; 1 point/thread. 1664x512 part layout —
// harness-verified in R16 (byte-identical to R15/R16 reduce).
__global__ __launch_bounds__(1024) void reduce_kernel(
    const float* __restrict__ part,
    const float* __restrict__ conf_in,   // pc1_3, 8192 values
    float* __restrict__ ws)
{
    int g = blockIdx.x;
    int tid = threadIdx.x;
    int i, nb, base; float scale; bool isconf = false;
    if (g < 8)       { i = (g << 10) + tid;        base = 0    + (i >> 9) * 32; nb = 32; scale = 0.5f / 8192.f; }
    else if (g < 16) { i = ((g - 8) << 10) + tid;  base = 512  + (i >> 9) * 32; nb = 32; scale = 0.5f / 8192.f; }
    else if (g < 20) { i = ((g - 16) << 10) + tid; base = 1024 + (i >> 9) * 32; nb = 32; scale = 1.f / 4096.f; }
    else if (g < 28) { i = ((g - 20) << 10) + tid; base = 1280 + (i >> 9) * 16; nb = 16; scale = 1.f / 8192.f; }
    else             { i = ((g - 28) << 10) + tid; int b = i >> 11; int w = i & 2047;
                       base = 1536 + b * 32 + (w >> 9) * 8; nb = 8; scale = 1.f / 8192.f; isconf = true; }

    float m = 3.4e38f;
    const float* p = part + base * 512 + (i & 511);
    #pragma unroll 4
    for (int t = 0; t < nb; t++, p += 512) m = fminf(m, p[0]);
    float d = sqrtf(m);
    float sum;
    if (!isconf) {
        sum = d;
    } else {
        float e = conf_in[i] - __expf(-d);
        sum = e * e;
    }
    #pragma unroll
    for (int ofs = 32; ofs > 0; ofs >>= 1) sum += __shfl_down(sum, ofs);
    __shared__ float red[16];
    if ((tid & 63) == 0) red[tid >> 6] = sum;
    __syncthreads();
    if (tid == 0) {
        float tot = 0.f;
        #pragma unroll
        for (int i2 = 0; i2 < 16; i2++) tot += red[i2];
        ws[g] = tot * scale;
    }
}

// out[b,n,m] = S + 0.5 * dist(pc1_0[b,n], pc2[b,m]).  UNCHANGED (BW floor).
__global__ __launch_bounds__(256) void out_kernel(
    const float* __restrict__ pc1_0,
    const float* __restrict__ pc2,
    const float* __restrict__ wsp,
    float* __restrict__ out)
{
    int blk = blockIdx.x;            // 1024 blocks
    int batch = blk >> 8;
    int n8 = blk & 255;
    int tid = threadIdx.x;
    float S = 0.f;
    #pragma unroll
    for (int t = 0; t < 36; t++) S += wsp[t];   // uniform -> s_loads
    const float* bb = pc2 + batch * 6144;
    float bx[8], by[8], bz[8];
    {
        const float4* p = (const float4*)(bb + tid * 12);
        float4 u0 = p[0], u1 = p[1], u2 = p[2];
        bx[0]=u0.x; by[0]=u0.y; bz[0]=u0.z;
        bx[1]=u0.w; by[1]=u1.x; bz[1]=u1.y;
        bx[2]=u1.z; by[2]=u1.w; bz[2]=u2.x;
        bx[3]=u2.y; by[3]=u2.z; bz[3]=u2.w;
    }
    {
        const float4* p = (const float4*)(bb + 3072 + tid * 12);
        float4 u0 = p[0], u1 = p[1], u2 = p[2];
        bx[4]=u0.x; by[4]=u0.y; bz[4]=u0.z;
        bx[5]=u0.w; by[5]=u1.x; bz[5]=u1.y;
        bx[6]=u1.z; by[6]=u1.w; bz[6]=u2.x;
        bx[7]=u2.y; by[7]=u2.z; bz[7]=u2.w;
    }
    const float* arow = pc1_0 + batch * 6144 + n8 * 24;  // 8 rows x 3 (uniform)
    float* ob = out + (long)((batch << 11) + (n8 << 3)) * 2048 + tid * 4;
    #pragma unroll
    for (int r = 0; r < 8; r++) {
        float axx = arow[r*3], ayy = arow[r*3+1], azz = arow[r*3+2];
        float o[8];
        #pragma unroll
        for (int k = 0; k < 8; k++) {
            float dx = axx - bx[k], dy = ayy - by[k], dz = azz - bz[k];
            float d2 = fmaf(dx, dx, fmaf(dy, dy, dz*dz));
            o[k] = fmaf(0.5f, sqrtf(d2), S);
        }
        nfloat4 lo = { o[0], o[1], o[2], o[3] };
        nfloat4 hi = { o[4], o[5], o[6], o[7] };
        __builtin_nontemporal_store(lo, (nfloat4*)(ob + r * 2048));
        __builtin_nontemporal_store(hi, (nfloat4*)(ob + r * 2048 + 1024));
    }
}

extern "C" void kernel_launch(void* const* d_in, const int* in_sizes, int n_in,
                              void* d_out, int out_size, void* d_ws, size_t ws_size,
                              hipStream_t stream) {
    const float* pc1_0 = (const float*)d_in[0];  // [4,2048,3]
    const float* pc1_1 = (const float*)d_in[1];  // [4,1024,3]
    const float* pc1_3 = (const float*)d_in[2];  // [4,2048,1]
    const float* pc2   = (const float*)d_in[3];  // [4,2048,3]
    const float* pc3   = (const float*)d_in[4];  // [4,2048,3]
    float* out = (float*)d_out;
    float* ws  = (float*)d_ws;                   // ws[0..35]: scaled partial sums
    float* part = out + PART_OFS;                // partial-min scratch in d_out tail

    nn_kernel<<<1664, 128, 0, stream>>>(pc1_0, pc1_1, pc2, pc3, part);
    reduce_kernel<<<36, 1024, 0, stream>>>(part, pc1_3, ws);
    out_kernel<<<1024, 256, 0, stream>>>(pc1_0, pc2, ws, out);
}